// Round 3
// baseline (276.317 us; speedup 1.0000x reference)
//
#include <hip/hip_runtime.h>

#define B_ 4
#define S_ 2048
#define D_ 1024
#define H_ 16
#define HD_ 64
#define M_ (B_*S_)      // 8192 rows
#define NQKV_ (3*D_)    // 3072

typedef _Float16 f16;
typedef __attribute__((ext_vector_type(8))) _Float16 f16x8;
typedef __attribute__((ext_vector_type(4))) float f32x4;

__device__ __forceinline__ void gload_lds16(const void* g, void* lds) {
  __builtin_amdgcn_global_load_lds(
      (const __attribute__((address_space(1))) void*)g,
      (__attribute__((address_space(3))) void*)lds, 16, 0, 0);
}

// ---------------- cast fp32 -> fp16, 8 elems/thread ----------------
__global__ void cast_kernel(const float* __restrict__ in, f16* __restrict__ out) {
  size_t i = (size_t)(blockIdx.x * 256 + threadIdx.x) * 8;
  float4 a = *reinterpret_cast<const float4*>(in + i);
  float4 b = *reinterpret_cast<const float4*>(in + i + 4);
  f16x8 o;
  o[0] = (f16)a.x; o[1] = (f16)a.y; o[2] = (f16)a.z; o[3] = (f16)a.w;
  o[4] = (f16)b.x; o[5] = (f16)b.y; o[6] = (f16)b.z; o[7] = (f16)b.w;
  *reinterpret_cast<f16x8*>(out + i) = o;
}

// ---------------- RoPE (in place on q,k), q also scaled by 1/8 ------
__global__ void rope_kernel(f16* __restrict__ q, f16* __restrict__ k,
                            const int* __restrict__ pos) {
  int idx = blockIdx.x * 256 + threadIdx.x;   // B_*H_*S_*32 threads, one (row,pair)
  int t = idx & 31;
  int srow = (idx >> 5) & (S_ - 1);
  float p = (float)pos[srow];
  float invf = exp2f((float)t * -0.4152410118609203f);  // -log2(10000)/32
  float ang = p * invf;
  float sn, cs;
  sincosf(ang, &sn, &cs);
  size_t base = ((size_t)(idx >> 5)) * HD_ + 2 * t;
  float x1 = (float)q[base], x2 = (float)q[base + 1];
  q[base]     = (f16)((x1 * cs - x2 * sn) * 0.125f);
  q[base + 1] = (f16)((x2 * cs + x1 * sn) * 0.125f);
  x1 = (float)k[base]; x2 = (float)k[base + 1];
  k[base]     = (f16)(x1 * cs - x2 * sn);
  k[base + 1] = (f16)(x2 * cs + x1 * sn);
}

// ---------------- V transpose: (B,H,S,hd) -> (B,H,hd,S) -------------
__global__ void vtrans_kernel(const f16* __restrict__ v, f16* __restrict__ vt) {
  __shared__ __align__(16) f16 tile[64][72];
  int tid = threadIdx.x;
  int bh = blockIdx.x >> 5;
  int s0 = (blockIdx.x & 31) << 6;
  const size_t vbase = ((size_t)bh * S_ + s0) * HD_;
  #pragma unroll
  for (int i = 0; i < 2; ++i) {
    int f = i * 256 + tid;
    int row = f >> 3, c8 = (f & 7) * 8;
    f16x8 val = *reinterpret_cast<const f16x8*>(v + vbase + (size_t)row * HD_ + c8);
    #pragma unroll
    for (int j = 0; j < 8; ++j) tile[row][c8 + j] = val[j];
  }
  __syncthreads();
  const size_t tbase = (size_t)bh * (HD_ * S_);
  #pragma unroll
  for (int i = 0; i < 2; ++i) {
    int f = i * 256 + tid;
    int d = f >> 3, c8 = (f & 7) * 8;
    f16x8 o;
    #pragma unroll
    for (int j = 0; j < 8; ++j) o[j] = tile[c8 + j][d];
    *reinterpret_cast<f16x8*>(vt + tbase + (size_t)d * S_ + s0 + c8) = o;
  }
}

// ---------------- GEMM C[m,n] = sum_k A[m,k]*Bt[n,k] ----------------
// MODE 0: scatter-write f16 into qkv (3,B,H,S,hd). MODE 1: fp32 linear.
template <int MODE>
__global__ __launch_bounds__(256)
void gemm_bt(const f16* __restrict__ A, const f16* __restrict__ Bt,
             void* __restrict__ Cout, int M, int N, int K) {
  __shared__ __align__(16) f16 As[128 * 64];
  __shared__ __align__(16) f16 Bs[128 * 64];
  const int tid = threadIdx.x;
  const int w = tid >> 6, l = tid & 63;
  const int nM = M >> 7;
  const int bm = (blockIdx.x % nM) << 7;
  const int bn = (blockIdx.x / nM) << 7;
  const int wr = (w >> 1) << 6;   // wave row offset in tile
  const int wc = (w & 1) << 6;    // wave col offset in tile
  const int lr = l & 15;
  const int lk = (l >> 4) << 3;
  const int orow = (l >> 4) << 2;
  const int srow = tid >> 3;            // staging row within 32-row chunk
  const int sc8 = (tid & 7) * 8;        // staging col (elems)

  f32x4 acc[4][4];
  #pragma unroll
  for (int i = 0; i < 4; ++i)
    #pragma unroll
    for (int j = 0; j < 4; ++j) acc[i][j] = f32x4{0.f, 0.f, 0.f, 0.f};

  for (int k0 = 0; k0 < K; k0 += 64) {
    __syncthreads();
    #pragma unroll
    for (int i = 0; i < 4; ++i) {
      gload_lds16(A + (size_t)(bm + i * 32 + srow) * K + k0 + sc8,
                  (void*)(As + (i * 256 + w * 64) * 8));
      gload_lds16(Bt + (size_t)(bn + i * 32 + srow) * K + k0 + sc8,
                  (void*)(Bs + (i * 256 + w * 64) * 8));
    }
    __syncthreads();
    #pragma unroll
    for (int t = 0; t < 2; ++t) {
      f16x8 af[4], bfr[4];
      #pragma unroll
      for (int mi = 0; mi < 4; ++mi)
        af[mi] = *reinterpret_cast<const f16x8*>(As + (wr + mi * 16 + lr) * 64 + t * 32 + lk);
      #pragma unroll
      for (int ni = 0; ni < 4; ++ni)
        bfr[ni] = *reinterpret_cast<const f16x8*>(Bs + (wc + ni * 16 + lr) * 64 + t * 32 + lk);
      #pragma unroll
      for (int mi = 0; mi < 4; ++mi)
        #pragma unroll
        for (int ni = 0; ni < 4; ++ni)
          acc[mi][ni] = __builtin_amdgcn_mfma_f32_16x16x32_f16(af[mi], bfr[ni], acc[mi][ni], 0, 0, 0);
    }
  }

  if (MODE == 0) {
    f16* qkv = (f16*)Cout;
    const size_t which_stride = (size_t)B_ * H_ * S_ * HD_;
    #pragma unroll
    for (int ni = 0; ni < 4; ++ni) {
      int n = bn + wc + ni * 16 + lr;
      int which = n >> 10, h = (n >> 6) & (H_ - 1), d = n & (HD_ - 1);
      size_t nb = (size_t)which * which_stride + (size_t)h * (S_ * HD_) + d;
      #pragma unroll
      for (int mi = 0; mi < 4; ++mi) {
        #pragma unroll
        for (int r = 0; r < 4; ++r) {
          int m = bm + wr + mi * 16 + orow + r;
          int b = m >> 11, s = m & (S_ - 1);
          qkv[nb + (size_t)b * (H_ * S_ * HD_) + (size_t)s * HD_] = (f16)acc[mi][ni][r];
        }
      }
    }
  } else {
    float* C = (float*)Cout;
    #pragma unroll
    for (int mi = 0; mi < 4; ++mi)
      #pragma unroll
      for (int r = 0; r < 4; ++r) {
        int m = bm + wr + mi * 16 + orow + r;
        #pragma unroll
        for (int ni = 0; ni < 4; ++ni) {
          int n = bn + wc + ni * 16 + lr;
          C[(size_t)m * N + n] = acc[mi][ni][r];
        }
      }
  }
}

// ---------------- flash attention (causal) --------------------------
// grid: 64 bh * 16 pairs. Each block processes TWO q-tiles: qt=31-p
// (heavy) then qt=p (light) -> exactly 33 KV-tile iters per block,
// perfect causal load balance. 4 waves, each owns 16 q-rows of the
// current q-tile. Q pre-scaled by 1/8.
// Ks/Vs are XOR-swizzled (col ^= (row&7)<<3 elems) via pre-swizzled
// global_load_lds source + swizzled ds_read (both-sides rule).
__global__ __launch_bounds__(256)
void attn_kernel(const f16* __restrict__ q, const f16* __restrict__ k,
                 const f16* __restrict__ vt, f16* __restrict__ attn_out) {
  __shared__ __align__(16) f16 Ks[64 * 64];
  __shared__ __align__(16) f16 Vs[64 * 64];   // [d][kv]
  __shared__ __align__(16) f16 Ps[4][16 * 72];
  const int tid = threadIdx.x, w = tid >> 6, l = tid & 63;
  const int lr = l & 15, lk = (l >> 4) << 3, orow = (l >> 4) << 2;
  const int bh = blockIdx.x & 63;
  const int pair = (int)(blockIdx.x >> 6);    // 0..15
  const size_t bhoff = (size_t)bh * (S_ * HD_);
  const size_t vtoff = (size_t)bh * (HD_ * S_);
  const int srow = tid >> 3;
  const int sc8 = (tid & 7) * 8;
  const int ssw = sc8 ^ ((srow & 7) << 3);    // swizzled source col (elems)
  const int swz = (lr & 7) << 3;              // read-side XOR (row&7)<<3
  const int h = bh & (H_ - 1), b = bh >> 4;

  for (int ph = 0; ph < 2; ++ph) {
    const int qt = ph ? pair : (31 - pair);
    const int q0 = qt << 6;

    f16x8 qf[2];
    #pragma unroll
    for (int t = 0; t < 2; ++t)
      qf[t] = *reinterpret_cast<const f16x8*>(q + bhoff + (size_t)(q0 + w * 16 + lr) * HD_ + t * 32 + lk);

    f32x4 o[4];
    float m_run[4], l_run[4];
    #pragma unroll
    for (int i = 0; i < 4; ++i) { o[i] = f32x4{0.f, 0.f, 0.f, 0.f}; m_run[i] = -1e30f; l_run[i] = 0.f; }

    const int ntiles = qt + 1;
    for (int it = 0; it < ntiles; ++it) {
      const int kv0 = it << 6;
      __syncthreads();
      #pragma unroll
      for (int i = 0; i < 2; ++i) {
        gload_lds16(k + bhoff + (size_t)(kv0 + i * 32 + srow) * HD_ + ssw,
                    (void*)(Ks + (i * 256 + w * 64) * 8));
        gload_lds16(vt + vtoff + (size_t)(i * 32 + srow) * S_ + kv0 + ssw,
                    (void*)(Vs + (i * 256 + w * 64) * 8));
      }
      __syncthreads();

      f32x4 sacc[4];
      #pragma unroll
      for (int ni = 0; ni < 4; ++ni) sacc[ni] = f32x4{0.f, 0.f, 0.f, 0.f};
      #pragma unroll
      for (int t = 0; t < 2; ++t) {
        #pragma unroll
        for (int ni = 0; ni < 4; ++ni) {
          f16x8 kf = *reinterpret_cast<const f16x8*>(Ks + (ni * 16 + lr) * 64 + ((t * 32 + lk) ^ swz));
          sacc[ni] = __builtin_amdgcn_mfma_f32_16x16x32_f16(qf[t], kf, sacc[ni], 0, 0, 0);
        }
      }
      if (it == ntiles - 1) {   // diagonal tile: causal mask
        #pragma unroll
        for (int ni = 0; ni < 4; ++ni) {
          int kvg = kv0 + ni * 16 + lr;
          #pragma unroll
          for (int r = 0; r < 4; ++r) {
            int qg = q0 + w * 16 + orow + r;
            if (kvg > qg) sacc[ni][r] = -1e30f;
          }
        }
      }
      // online softmax (rows live in 4 regs, replicated across 16 lanes)
      float pm[4];
      #pragma unroll
      for (int r = 0; r < 4; ++r)
        pm[r] = fmaxf(fmaxf(sacc[0][r], sacc[1][r]), fmaxf(sacc[2][r], sacc[3][r]));
      #pragma unroll
      for (int off = 1; off < 16; off <<= 1)
        #pragma unroll
        for (int r = 0; r < 4; ++r) pm[r] = fmaxf(pm[r], __shfl_xor(pm[r], off));
      float sc_[4], rs[4];
      #pragma unroll
      for (int r = 0; r < 4; ++r) {
        float mn = fmaxf(m_run[r], pm[r]);
        sc_[r] = __expf(m_run[r] - mn);
        m_run[r] = mn;
      }
      #pragma unroll
      for (int ni = 0; ni < 4; ++ni)
        #pragma unroll
        for (int r = 0; r < 4; ++r) sacc[ni][r] = __expf(sacc[ni][r] - m_run[r]);
      #pragma unroll
      for (int r = 0; r < 4; ++r) rs[r] = sacc[0][r] + sacc[1][r] + sacc[2][r] + sacc[3][r];
      #pragma unroll
      for (int off = 1; off < 16; off <<= 1)
        #pragma unroll
        for (int r = 0; r < 4; ++r) rs[r] += __shfl_xor(rs[r], off);
      #pragma unroll
      for (int r = 0; r < 4; ++r) l_run[r] = l_run[r] * sc_[r] + rs[r];
      #pragma unroll
      for (int ni = 0; ni < 4; ++ni)
        #pragma unroll
        for (int r = 0; r < 4; ++r) o[ni][r] *= sc_[r];

      // P -> LDS (transpose D-layout -> A-layout), per-wave PRIVATE region:
      // no barrier needed — program-order lgkmcnt covers write->read in-wave.
      #pragma unroll
      for (int ni = 0; ni < 4; ++ni)
        #pragma unroll
        for (int r = 0; r < 4; ++r)
          Ps[w][(orow + r) * 72 + ni * 16 + lr] = (f16)sacc[ni][r];

      // PV
      #pragma unroll
      for (int t = 0; t < 2; ++t) {
        f16x8 pf = *reinterpret_cast<const f16x8*>(&Ps[w][lr * 72 + t * 32 + lk]);
        #pragma unroll
        for (int ni = 0; ni < 4; ++ni) {
          f16x8 vf = *reinterpret_cast<const f16x8*>(Vs + (ni * 16 + lr) * 64 + ((t * 32 + lk) ^ swz));
          o[ni] = __builtin_amdgcn_mfma_f32_16x16x32_f16(pf, vf, o[ni], 0, 0, 0);
        }
      }
    }

    float rl[4];
    #pragma unroll
    for (int r = 0; r < 4; ++r) rl[r] = 1.0f / l_run[r];
    #pragma unroll
    for (int ni = 0; ni < 4; ++ni) {
      int dcol = ni * 16 + lr;
      #pragma unroll
      for (int r = 0; r < 4; ++r) {
        int qg = q0 + w * 16 + orow + r;
        attn_out[((size_t)(b * S_ + qg)) * D_ + h * HD_ + dcol] = (f16)(o[ni][r] * rl[r]);
      }
    }
  }
}

// ---------------- launch --------------------------------------------
extern "C" void kernel_launch(void* const* d_in, const int* in_sizes, int n_in,
                              void* d_out, int out_size, void* d_ws, size_t ws_size,
                              hipStream_t stream) {
  const float* x    = (const float*)d_in[0];
  const int*   pos  = (const int*)d_in[1];
  const float* wqkv = (const float*)d_in[2];
  const float* wo   = (const float*)d_in[3];
  float* out = (float*)d_out;

  const size_t BHSD = (size_t)B_ * H_ * S_ * HD_;   // 8388608
  f16* xb    = (f16*)d_ws;                 // M_*D_
  f16* wqkvb = xb + (size_t)M_ * D_;       // NQKV_*D_
  f16* wob   = wqkvb + (size_t)NQKV_ * D_; // D_*D_
  f16* qb    = wob + (size_t)D_ * D_;      // qkv: 3 * BHSD
  f16* kb    = qb + BHSD;
  f16* vb    = kb + BHSD;
  f16* vtb   = vb + BHSD;                  // BHSD
  f16* attnb = vtb + BHSD;                 // BHSD
  // total ~104 MB of d_ws

  cast_kernel<<<(M_ * D_) / 2048, 256, 0, stream>>>(x, xb);
  cast_kernel<<<(NQKV_ * D_) / 2048, 256, 0, stream>>>(wqkv, wqkvb);
  cast_kernel<<<(D_ * D_) / 2048, 256, 0, stream>>>(wo, wob);

  gemm_bt<0><<<(M_ / 128) * (NQKV_ / 128), 256, 0, stream>>>(xb, wqkvb, (void*)qb, M_, NQKV_, D_);

  rope_kernel<<<(B_ * H_ * S_ * 32) / 256, 256, 0, stream>>>(qb, kb, pos);
  vtrans_kernel<<<B_ * H_ * (S_ / 64), 256, 0, stream>>>(vb, vtb);

  attn_kernel<<<64 * 16, 256, 0, stream>>>(qb, kb, vtb, attnb);

  gemm_bt<1><<<(M_ / 128) * (D_ / 128), 256, 0, stream>>>(attnb, wob, (void*)out, M_, D_, D_);
}

// Round 4
// 225.354 us; speedup vs baseline: 1.2261x; 1.2261x over previous
//
#include <hip/hip_runtime.h>

#define B_ 4
#define S_ 2048
#define D_ 1024
#define H_ 16
#define HD_ 64
#define M_ (B_*S_)      // 8192 rows
#define NQKV_ (3*D_)    // 3072

typedef _Float16 f16;
typedef __attribute__((ext_vector_type(4))) _Float16 f16x4;
typedef __attribute__((ext_vector_type(8))) _Float16 f16x8;
typedef __attribute__((ext_vector_type(4))) float f32x4;

__device__ __forceinline__ void gload_lds16(const void* g, void* lds) {
  __builtin_amdgcn_global_load_lds(
      (const __attribute__((address_space(1))) void*)g,
      (__attribute__((address_space(3))) void*)lds, 16, 0, 0);
}

// ---------------- cast fp32 -> fp16, 8 elems/thread ----------------
__global__ void cast_kernel(const float* __restrict__ in, f16* __restrict__ out) {
  size_t i = (size_t)(blockIdx.x * 256 + threadIdx.x) * 8;
  float4 a = *reinterpret_cast<const float4*>(in + i);
  float4 b = *reinterpret_cast<const float4*>(in + i + 4);
  f16x8 o;
  o[0] = (f16)a.x; o[1] = (f16)a.y; o[2] = (f16)a.z; o[3] = (f16)a.w;
  o[4] = (f16)b.x; o[5] = (f16)b.y; o[6] = (f16)b.z; o[7] = (f16)b.w;
  *reinterpret_cast<f16x8*>(out + i) = o;
}

// ---------------- RoPE (in place on q,k) ---------------------------
// q additionally scaled by (1/8)*log2(e) so attention works in exp2 domain.
__global__ void rope_kernel(f16* __restrict__ q, f16* __restrict__ k,
                            const int* __restrict__ pos) {
  int idx = blockIdx.x * 256 + threadIdx.x;   // B_*H_*S_*32 threads, one (row,pair)
  int t = idx & 31;
  int srow = (idx >> 5) & (S_ - 1);
  float p = (float)pos[srow];
  float invf = exp2f((float)t * -0.4152410118609203f);  // -log2(10000)/32
  float ang = p * invf;
  float sn, cs;
  sincosf(ang, &sn, &cs);
  const float qs = 0.125f * 1.4426950408889634f;        // (1/sqrt(64))*log2(e)
  size_t base = ((size_t)(idx >> 5)) * HD_ + 2 * t;
  float x1 = (float)q[base], x2 = (float)q[base + 1];
  q[base]     = (f16)((x1 * cs - x2 * sn) * qs);
  q[base + 1] = (f16)((x2 * cs + x1 * sn) * qs);
  x1 = (float)k[base]; x2 = (float)k[base + 1];
  k[base]     = (f16)(x1 * cs - x2 * sn);
  k[base + 1] = (f16)(x2 * cs + x1 * sn);
}

// ---------------- V transpose: (B,H,S,hd) -> (B,H,hd,S) -------------
__global__ void vtrans_kernel(const f16* __restrict__ v, f16* __restrict__ vt) {
  __shared__ __align__(16) f16 tile[64][72];
  int tid = threadIdx.x;
  int bh = blockIdx.x >> 5;
  int s0 = (blockIdx.x & 31) << 6;
  const size_t vbase = ((size_t)bh * S_ + s0) * HD_;
  #pragma unroll
  for (int i = 0; i < 2; ++i) {
    int f = i * 256 + tid;
    int row = f >> 3, c8 = (f & 7) * 8;
    f16x8 val = *reinterpret_cast<const f16x8*>(v + vbase + (size_t)row * HD_ + c8);
    #pragma unroll
    for (int j = 0; j < 8; ++j) tile[row][c8 + j] = val[j];
  }
  __syncthreads();
  const size_t tbase = (size_t)bh * (HD_ * S_);
  #pragma unroll
  for (int i = 0; i < 2; ++i) {
    int f = i * 256 + tid;
    int d = f >> 3, c8 = (f & 7) * 8;
    f16x8 o;
    #pragma unroll
    for (int j = 0; j < 8; ++j) o[j] = tile[c8 + j][d];
    *reinterpret_cast<f16x8*>(vt + tbase + (size_t)d * S_ + s0 + c8) = o;
  }
}

// ---------------- GEMM C[m,n] = sum_k A[m,k]*Bt[n,k] ----------------
// MODE 0: scatter-write f16 into qkv (3,B,H,S,hd). MODE 1: fp32 linear.
template <int MODE>
__global__ __launch_bounds__(256)
void gemm_bt(const f16* __restrict__ A, const f16* __restrict__ Bt,
             void* __restrict__ Cout, int M, int N, int K) {
  __shared__ __align__(16) f16 As[128 * 64];
  __shared__ __align__(16) f16 Bs[128 * 64];
  const int tid = threadIdx.x;
  const int w = tid >> 6, l = tid & 63;
  const int nM = M >> 7;
  const int bm = (blockIdx.x % nM) << 7;
  const int bn = (blockIdx.x / nM) << 7;
  const int wr = (w >> 1) << 6;   // wave row offset in tile
  const int wc = (w & 1) << 6;    // wave col offset in tile
  const int lr = l & 15;
  const int lk = (l >> 4) << 3;
  const int orow = (l >> 4) << 2;
  const int srow = tid >> 3;            // staging row within 32-row chunk
  const int sc8 = (tid & 7) * 8;        // staging col (elems)

  f32x4 acc[4][4];
  #pragma unroll
  for (int i = 0; i < 4; ++i)
    #pragma unroll
    for (int j = 0; j < 4; ++j) acc[i][j] = f32x4{0.f, 0.f, 0.f, 0.f};

  for (int k0 = 0; k0 < K; k0 += 64) {
    __syncthreads();
    #pragma unroll
    for (int i = 0; i < 4; ++i) {
      gload_lds16(A + (size_t)(bm + i * 32 + srow) * K + k0 + sc8,
                  (void*)(As + (i * 256 + w * 64) * 8));
      gload_lds16(Bt + (size_t)(bn + i * 32 + srow) * K + k0 + sc8,
                  (void*)(Bs + (i * 256 + w * 64) * 8));
    }
    __syncthreads();
    #pragma unroll
    for (int t = 0; t < 2; ++t) {
      f16x8 af[4], bfr[4];
      #pragma unroll
      for (int mi = 0; mi < 4; ++mi)
        af[mi] = *reinterpret_cast<const f16x8*>(As + (wr + mi * 16 + lr) * 64 + t * 32 + lk);
      #pragma unroll
      for (int ni = 0; ni < 4; ++ni)
        bfr[ni] = *reinterpret_cast<const f16x8*>(Bs + (wc + ni * 16 + lr) * 64 + t * 32 + lk);
      #pragma unroll
      for (int mi = 0; mi < 4; ++mi)
        #pragma unroll
        for (int ni = 0; ni < 4; ++ni)
          acc[mi][ni] = __builtin_amdgcn_mfma_f32_16x16x32_f16(af[mi], bfr[ni], acc[mi][ni], 0, 0, 0);
    }
  }

  if (MODE == 0) {
    f16* qkv = (f16*)Cout;
    const size_t which_stride = (size_t)B_ * H_ * S_ * HD_;
    #pragma unroll
    for (int ni = 0; ni < 4; ++ni) {
      int n = bn + wc + ni * 16 + lr;
      int which = n >> 10, h = (n >> 6) & (H_ - 1), d = n & (HD_ - 1);
      size_t nb = (size_t)which * which_stride + (size_t)h * (S_ * HD_) + d;
      #pragma unroll
      for (int mi = 0; mi < 4; ++mi) {
        #pragma unroll
        for (int r = 0; r < 4; ++r) {
          int m = bm + wr + mi * 16 + orow + r;
          int b = m >> 11, s = m & (S_ - 1);
          qkv[nb + (size_t)b * (H_ * S_ * HD_) + (size_t)s * HD_] = (f16)acc[mi][ni][r];
        }
      }
    }
  } else {
    float* C = (float*)Cout;
    #pragma unroll
    for (int mi = 0; mi < 4; ++mi)
      #pragma unroll
      for (int r = 0; r < 4; ++r) {
        int m = bm + wr + mi * 16 + orow + r;
        #pragma unroll
        for (int ni = 0; ni < 4; ++ni) {
          int n = bn + wc + ni * 16 + lr;
          C[(size_t)m * N + n] = acc[mi][ni][r];
        }
      }
  }
}

// ---------------- flash attention (causal), swapped-operand form ----
// grid: (S/64) * (B*H), heavy q-tiles first. 4 waves, each owns 16
// q-rows. Computes S^T = mfma(K,Q) so each lane holds a full q-row of
// scores in registers: softmax row-reduce = in-reg tree + 2 shuffles
// (was 4-step trees x 8). m/l/scale are per-lane scalars. PV computes
// O^T = mfma(V^T, P^T). Q pre-scaled by (1/8)*log2e -> exp2 domain.
// Ks/Vs XOR-swizzled (col ^= (row&7)<<3) via pre-swizzled gload src +
// swizzled ds_read (both-sides rule).
__global__ __launch_bounds__(256)
void attn_kernel(const f16* __restrict__ q, const f16* __restrict__ k,
                 const f16* __restrict__ vt, f16* __restrict__ attn_out) {
  __shared__ __align__(16) f16 Ks[64 * 64];
  __shared__ __align__(16) f16 Vs[64 * 64];   // [d][kv]
  __shared__ __align__(16) f16 Ps[4][16 * 72];
  const int tid = threadIdx.x, w = tid >> 6, l = tid & 63;
  const int lr = l & 15, lk = (l >> 4) << 3, orow = (l >> 4) << 2;
  const int bh = blockIdx.x & 63;
  const int qt = 31 - (int)(blockIdx.x >> 6); // heavy tiles first
  const int q0 = qt << 6;
  const size_t bhoff = (size_t)bh * (S_ * HD_);
  const size_t vtoff = (size_t)bh * (HD_ * S_);
  const int srow = tid >> 3;
  const int sc8 = (tid & 7) * 8;
  const int ssw = sc8 ^ ((srow & 7) << 3);    // swizzled source col (elems)
  const int swz = (lr & 7) << 3;              // read-side XOR (row&7)<<3
  const int h = bh & (H_ - 1), b = bh >> 4;
  const int qg = q0 + w * 16 + lr;            // this lane's q-row

  f16x8 qf[2];
  #pragma unroll
  for (int t = 0; t < 2; ++t)
    qf[t] = *reinterpret_cast<const f16x8*>(q + bhoff + (size_t)qg * HD_ + t * 32 + lk);

  f32x4 o[4];
  float m_run = -1e30f, l_run = 0.f;
  #pragma unroll
  for (int i = 0; i < 4; ++i) o[i] = f32x4{0.f, 0.f, 0.f, 0.f};

  const int ntiles = qt + 1;
  for (int it = 0; it < ntiles; ++it) {
    const int kv0 = it << 6;
    __syncthreads();
    #pragma unroll
    for (int i = 0; i < 2; ++i) {
      gload_lds16(k + bhoff + (size_t)(kv0 + i * 32 + srow) * HD_ + ssw,
                  (void*)(Ks + (i * 256 + w * 64) * 8));
      gload_lds16(vt + vtoff + (size_t)(i * 32 + srow) * S_ + kv0 + ssw,
                  (void*)(Vs + (i * 256 + w * 64) * 8));
    }
    __syncthreads();

    // S^T: D[col=q=lr][row=kv=ni*16+orow+r]
    f32x4 sacc[4];
    #pragma unroll
    for (int ni = 0; ni < 4; ++ni) sacc[ni] = f32x4{0.f, 0.f, 0.f, 0.f};
    #pragma unroll
    for (int t = 0; t < 2; ++t) {
      #pragma unroll
      for (int ni = 0; ni < 4; ++ni) {
        f16x8 kf = *reinterpret_cast<const f16x8*>(Ks + (ni * 16 + lr) * 64 + ((t * 32 + lk) ^ swz));
        sacc[ni] = __builtin_amdgcn_mfma_f32_16x16x32_f16(kf, qf[t], sacc[ni], 0, 0, 0);
      }
    }
    if (it == ntiles - 1) {   // diagonal tile: causal mask (kv in rows now)
      #pragma unroll
      for (int ni = 0; ni < 4; ++ni) {
        #pragma unroll
        for (int r = 0; r < 4; ++r) {
          int kvg = kv0 + ni * 16 + orow + r;
          if (kvg > qg) sacc[ni][r] = -1e30f;
        }
      }
    }

    // online softmax: lane-local row (16 vals) + 2 shuffles across groups
    f32x4 m4 = sacc[0];
    #pragma unroll
    for (int ni = 1; ni < 4; ++ni)
      #pragma unroll
      for (int r = 0; r < 4; ++r) m4[r] = fmaxf(m4[r], sacc[ni][r]);
    float mloc = fmaxf(fmaxf(m4[0], m4[1]), fmaxf(m4[2], m4[3]));
    mloc = fmaxf(mloc, __shfl_xor(mloc, 16));
    mloc = fmaxf(mloc, __shfl_xor(mloc, 32));
    float mn = fmaxf(m_run, mloc);
    float scale = exp2f(m_run - mn);
    m_run = mn;
    #pragma unroll
    for (int ni = 0; ni < 4; ++ni)
      #pragma unroll
      for (int r = 0; r < 4; ++r) sacc[ni][r] = exp2f(sacc[ni][r] - mn);
    f32x4 s4 = sacc[0];
    #pragma unroll
    for (int ni = 1; ni < 4; ++ni)
      #pragma unroll
      for (int r = 0; r < 4; ++r) s4[r] += sacc[ni][r];
    float sloc = (s4[0] + s4[1]) + (s4[2] + s4[3]);
    sloc += __shfl_xor(sloc, 16);
    sloc += __shfl_xor(sloc, 32);
    l_run = l_run * scale + sloc;
    #pragma unroll
    for (int ni = 0; ni < 4; ++ni)
      #pragma unroll
      for (int r = 0; r < 4; ++r) o[ni][r] *= scale;

    // P^T -> LDS as row-major P[q][kv], packed b64 writes (wave-private,
    // program-order lgkmcnt covers write->read, no barrier needed)
    #pragma unroll
    for (int ni = 0; ni < 4; ++ni) {
      f16x4 pk;
      #pragma unroll
      for (int r = 0; r < 4; ++r) pk[r] = (f16)sacc[ni][r];
      *reinterpret_cast<f16x4*>(&Ps[w][lr * 72 + ni * 16 + orow]) = pk;
    }

    // O^T += V^T * P^T
    #pragma unroll
    for (int t = 0; t < 2; ++t) {
      f16x8 pf = *reinterpret_cast<const f16x8*>(&Ps[w][lr * 72 + t * 32 + lk]);
      #pragma unroll
      for (int ni = 0; ni < 4; ++ni) {
        f16x8 vf = *reinterpret_cast<const f16x8*>(Vs + (ni * 16 + lr) * 64 + ((t * 32 + lk) ^ swz));
        o[ni] = __builtin_amdgcn_mfma_f32_16x16x32_f16(vf, pf, o[ni], 0, 0, 0);
      }
    }
  }

  // epilogue: O^T D-layout = [col=q=lr][row=d=ni*16+orow+r] -> packed stores
  float rl = 1.0f / l_run;
  #pragma unroll
  for (int ni = 0; ni < 4; ++ni) {
    f16x4 ov;
    #pragma unroll
    for (int r = 0; r < 4; ++r) ov[r] = (f16)(o[ni][r] * rl);
    *reinterpret_cast<f16x4*>(
        &attn_out[(size_t)(b * S_ + qg) * D_ + h * HD_ + ni * 16 + orow]) = ov;
  }
}

// ---------------- launch --------------------------------------------
extern "C" void kernel_launch(void* const* d_in, const int* in_sizes, int n_in,
                              void* d_out, int out_size, void* d_ws, size_t ws_size,
                              hipStream_t stream) {
  const float* x    = (const float*)d_in[0];
  const int*   pos  = (const int*)d_in[1];
  const float* wqkv = (const float*)d_in[2];
  const float* wo   = (const float*)d_in[3];
  float* out = (float*)d_out;

  const size_t BHSD = (size_t)B_ * H_ * S_ * HD_;   // 8388608
  f16* xb    = (f16*)d_ws;                 // M_*D_
  f16* wqkvb = xb + (size_t)M_ * D_;       // NQKV_*D_
  f16* wob   = wqkvb + (size_t)NQKV_ * D_; // D_*D_
  f16* qb    = wob + (size_t)D_ * D_;      // qkv: 3 * BHSD
  f16* kb    = qb + BHSD;
  f16* vb    = kb + BHSD;
  f16* vtb   = vb + BHSD;                  // BHSD
  f16* attnb = vtb + BHSD;                 // BHSD
  // total ~104 MB of d_ws

  cast_kernel<<<(M_ * D_) / 2048, 256, 0, stream>>>(x, xb);
  cast_kernel<<<(NQKV_ * D_) / 2048, 256, 0, stream>>>(wqkv, wqkvb);
  cast_kernel<<<(D_ * D_) / 2048, 256, 0, stream>>>(wo, wob);

  gemm_bt<0><<<(M_ / 128) * (NQKV_ / 128), 256, 0, stream>>>(xb, wqkvb, (void*)qb, M_, NQKV_, D_);

  rope_kernel<<<(B_ * H_ * S_ * 32) / 256, 256, 0, stream>>>(qb, kb, pos);
  vtrans_kernel<<<B_ * H_ * (S_ / 64), 256, 0, stream>>>(vb, vtb);

  attn_kernel<<<64 * 32, 256, 0, stream>>>(qb, kb, vtb, attnb);

  gemm_bt<1><<<(M_ / 128) * (D_ / 128), 256, 0, stream>>>(attnb, wob, (void*)out, M_, D_, D_);
}

// Round 5
// 216.168 us; speedup vs baseline: 1.2782x; 1.0425x over previous
//
#include <hip/hip_runtime.h>

#define B_ 4
#define S_ 2048
#define D_ 1024
#define H_ 16
#define HD_ 64
#define M_ (B_*S_)      // 8192 rows
#define NQKV_ (3*D_)    // 3072

typedef _Float16 f16;
typedef __attribute__((ext_vector_type(4))) _Float16 f16x4;
typedef __attribute__((ext_vector_type(8))) _Float16 f16x8;
typedef __attribute__((ext_vector_type(4))) float f32x4;

__device__ __forceinline__ void gload_lds16(const void* g, void* lds) {
  __builtin_amdgcn_global_load_lds(
      (const __attribute__((address_space(1))) void*)g,
      (__attribute__((address_space(3))) void*)lds, 16, 0, 0);
}

// ---------------- cast fp32 -> fp16, 8 elems/thread ----------------
__global__ void cast_kernel(const float* __restrict__ in, f16* __restrict__ out) {
  size_t i = (size_t)(blockIdx.x * 256 + threadIdx.x) * 8;
  float4 a = *reinterpret_cast<const float4*>(in + i);
  float4 b = *reinterpret_cast<const float4*>(in + i + 4);
  f16x8 o;
  o[0] = (f16)a.x; o[1] = (f16)a.y; o[2] = (f16)a.z; o[3] = (f16)a.w;
  o[4] = (f16)b.x; o[5] = (f16)b.y; o[6] = (f16)b.z; o[7] = (f16)b.w;
  *reinterpret_cast<f16x8*>(out + i) = o;
}

// ---------------- RoPE trig table: tab[s][t] = {cos,sin}(pos[s]*invf(t))
__global__ void trig_kernel(const int* __restrict__ pos, float2* __restrict__ tab) {
  int idx = blockIdx.x * 256 + threadIdx.x;   // S_*32 threads
  int s = idx >> 5, t = idx & 31;
  float p = (float)pos[s];
  float invf = exp2f((float)t * -0.4152410118609203f);  // -log2(10000)/32
  float sn, cs;
  sincosf(p * invf, &sn, &cs);
  tab[idx] = float2{cs, sn};
}

// ---------------- GEMM C[m,n] = sum_k A[m,k]*Bt[n,k], swapped-operand
// D-fragment: col=lr -> output row m, row-reg (orow+r) -> output col n,
// so each lane holds 4 CONSECUTIVE n. (Mapping verified by attn S^T.)
// MODE 0 (QKV): n in [0,1024)=Q -> rope*qs -> q(B,H,S,hd);
//               [1024,2048)=K -> rope -> k(B,H,S,hd);
//               [2048,3072)=V -> transposed write vt(B,H,hd,S).
// MODE 1: fp32 C row-major, float4 stores.
template <int MODE>
__global__ __launch_bounds__(256)
void gemm_bt(const f16* __restrict__ A, const f16* __restrict__ Bt,
             void* __restrict__ Cout, const float2* __restrict__ tab,
             f16* __restrict__ kout, f16* __restrict__ vtout,
             int M, int N, int K) {
  __shared__ __align__(16) f16 As[128 * 64];
  __shared__ __align__(16) f16 Bs[128 * 64];
  const int tid = threadIdx.x;
  const int w = tid >> 6, l = tid & 63;
  const int nM = M >> 7;
  const int bm = (blockIdx.x % nM) << 7;
  const int bn = (blockIdx.x / nM) << 7;
  const int wr = (w >> 1) << 6;   // wave row offset in tile
  const int wc = (w & 1) << 6;    // wave col offset in tile
  const int lr = l & 15;
  const int lk = (l >> 4) << 3;
  const int orow = (l >> 4) << 2;
  const int srow = tid >> 3;            // staging row within 32-row chunk
  const int sc8 = (tid & 7) * 8;        // staging col (elems)

  f32x4 acc[4][4];
  #pragma unroll
  for (int i = 0; i < 4; ++i)
    #pragma unroll
    for (int j = 0; j < 4; ++j) acc[i][j] = f32x4{0.f, 0.f, 0.f, 0.f};

  for (int k0 = 0; k0 < K; k0 += 64) {
    __syncthreads();
    #pragma unroll
    for (int i = 0; i < 4; ++i) {
      gload_lds16(A + (size_t)(bm + i * 32 + srow) * K + k0 + sc8,
                  (void*)(As + (i * 256 + w * 64) * 8));
      gload_lds16(Bt + (size_t)(bn + i * 32 + srow) * K + k0 + sc8,
                  (void*)(Bs + (i * 256 + w * 64) * 8));
    }
    __syncthreads();
    #pragma unroll
    for (int t = 0; t < 2; ++t) {
      f16x8 af[4], bfr[4];
      #pragma unroll
      for (int mi = 0; mi < 4; ++mi)
        af[mi] = *reinterpret_cast<const f16x8*>(As + (wr + mi * 16 + lr) * 64 + t * 32 + lk);
      #pragma unroll
      for (int ni = 0; ni < 4; ++ni)
        bfr[ni] = *reinterpret_cast<const f16x8*>(Bs + (wc + ni * 16 + lr) * 64 + t * 32 + lk);
      #pragma unroll
      for (int mi = 0; mi < 4; ++mi)
        #pragma unroll
        for (int ni = 0; ni < 4; ++ni)
          acc[mi][ni] = __builtin_amdgcn_mfma_f32_16x16x32_f16(bfr[ni], af[mi], acc[mi][ni], 0, 0, 0);
    }
  }

  if (MODE == 0) {
    const int which = bn >> 10;                 // uniform per block
    const int h = ((bn + wc) >> 6) & (H_ - 1);  // uniform per wave
    if (which < 2) {                            // Q or K: fused RoPE
      f16* dst = which ? kout : (f16*)Cout;
      const float qs = which ? 1.0f : 0.125f * 1.4426950408889634f;  // (1/8)*log2e
      #pragma unroll
      for (int mi = 0; mi < 4; ++mi) {
        int m = bm + wr + mi * 16 + lr;
        int b = m >> 11, s = m & (S_ - 1);
        size_t rowbase = ((size_t)(b * H_ + h) * S_ + s) * HD_;
        const float4* trow = reinterpret_cast<const float4*>(tab + (size_t)s * 32);
        #pragma unroll
        for (int ni = 0; ni < 4; ++ni) {
          int d0 = ni * 16 + orow;              // multiple of 4
          float4 cssn = trow[d0 >> 2];          // {cos(t0),sin(t0),cos(t0+1),sin(t0+1)}
          float x0 = acc[mi][ni][0], x1 = acc[mi][ni][1];
          float x2 = acc[mi][ni][2], x3 = acc[mi][ni][3];
          f16x4 ov;
          ov[0] = (f16)((x0 * cssn.x - x1 * cssn.y) * qs);
          ov[1] = (f16)((x1 * cssn.x + x0 * cssn.y) * qs);
          ov[2] = (f16)((x2 * cssn.z - x3 * cssn.w) * qs);
          ov[3] = (f16)((x3 * cssn.z + x2 * cssn.w) * qs);
          *reinterpret_cast<f16x4*>(&dst[rowbase + d0]) = ov;
        }
      }
    } else {                                    // V: direct transposed write
      #pragma unroll
      for (int mi = 0; mi < 4; ++mi) {
        int m = bm + wr + mi * 16 + lr;
        int b = m >> 11, s = m & (S_ - 1);
        size_t base = (size_t)(b * H_ + h) * (HD_ * S_) + s;
        #pragma unroll
        for (int ni = 0; ni < 4; ++ni)
          #pragma unroll
          for (int r = 0; r < 4; ++r)
            vtout[base + (size_t)(ni * 16 + orow + r) * S_] = (f16)acc[mi][ni][r];
      }
    }
  } else {
    float* C = (float*)Cout;
    #pragma unroll
    for (int mi = 0; mi < 4; ++mi) {
      int m = bm + wr + mi * 16 + lr;
      #pragma unroll
      for (int ni = 0; ni < 4; ++ni) {
        int n = bn + wc + ni * 16 + orow;
        *reinterpret_cast<float4*>(&C[(size_t)m * N + n]) =
            float4{acc[mi][ni][0], acc[mi][ni][1], acc[mi][ni][2], acc[mi][ni][3]};
      }
    }
  }
}

// ---------------- flash attention (causal), swapped-operand form ----
// grid: (S/64) * (B*H), heavy q-tiles first. 4 waves, each owns 16
// q-rows. S^T = mfma(K,Q): lane holds a full q-row of scores. Q
// pre-scaled by (1/8)*log2e -> exp2 domain. Ks/Vs XOR-swizzled.
__global__ __launch_bounds__(256)
void attn_kernel(const f16* __restrict__ q, const f16* __restrict__ k,
                 const f16* __restrict__ vt, f16* __restrict__ attn_out) {
  __shared__ __align__(16) f16 Ks[64 * 64];
  __shared__ __align__(16) f16 Vs[64 * 64];   // [d][kv]
  __shared__ __align__(16) f16 Ps[4][16 * 72];
  const int tid = threadIdx.x, w = tid >> 6, l = tid & 63;
  const int lr = l & 15, lk = (l >> 4) << 3, orow = (l >> 4) << 2;
  const int bh = blockIdx.x & 63;
  const int qt = 31 - (int)(blockIdx.x >> 6); // heavy tiles first
  const int q0 = qt << 6;
  const size_t bhoff = (size_t)bh * (S_ * HD_);
  const size_t vtoff = (size_t)bh * (HD_ * S_);
  const int srow = tid >> 3;
  const int sc8 = (tid & 7) * 8;
  const int ssw = sc8 ^ ((srow & 7) << 3);    // swizzled source col (elems)
  const int swz = (lr & 7) << 3;              // read-side XOR (row&7)<<3
  const int h = bh & (H_ - 1), b = bh >> 4;
  const int qg = q0 + w * 16 + lr;            // this lane's q-row

  f16x8 qf[2];
  #pragma unroll
  for (int t = 0; t < 2; ++t)
    qf[t] = *reinterpret_cast<const f16x8*>(q + bhoff + (size_t)qg * HD_ + t * 32 + lk);

  f32x4 o[4];
  float m_run = -1e30f, l_run = 0.f;
  #pragma unroll
  for (int i = 0; i < 4; ++i) o[i] = f32x4{0.f, 0.f, 0.f, 0.f};

  const int ntiles = qt + 1;
  for (int it = 0; it < ntiles; ++it) {
    const int kv0 = it << 6;
    __syncthreads();
    #pragma unroll
    for (int i = 0; i < 2; ++i) {
      gload_lds16(k + bhoff + (size_t)(kv0 + i * 32 + srow) * HD_ + ssw,
                  (void*)(Ks + (i * 256 + w * 64) * 8));
      gload_lds16(vt + vtoff + (size_t)(i * 32 + srow) * S_ + kv0 + ssw,
                  (void*)(Vs + (i * 256 + w * 64) * 8));
    }
    __syncthreads();

    // S^T: D[col=q=lr][row=kv=ni*16+orow+r]
    f32x4 sacc[4];
    #pragma unroll
    for (int ni = 0; ni < 4; ++ni) sacc[ni] = f32x4{0.f, 0.f, 0.f, 0.f};
    #pragma unroll
    for (int t = 0; t < 2; ++t) {
      #pragma unroll
      for (int ni = 0; ni < 4; ++ni) {
        f16x8 kf = *reinterpret_cast<const f16x8*>(Ks + (ni * 16 + lr) * 64 + ((t * 32 + lk) ^ swz));
        sacc[ni] = __builtin_amdgcn_mfma_f32_16x16x32_f16(kf, qf[t], sacc[ni], 0, 0, 0);
      }
    }
    if (it == ntiles - 1) {   // diagonal tile: causal mask (kv in rows)
      #pragma unroll
      for (int ni = 0; ni < 4; ++ni) {
        #pragma unroll
        for (int r = 0; r < 4; ++r) {
          int kvg = kv0 + ni * 16 + orow + r;
          if (kvg > qg) sacc[ni][r] = -1e30f;
        }
      }
    }

    // online softmax: lane-local row (16 vals) + 2 shuffles
    f32x4 m4 = sacc[0];
    #pragma unroll
    for (int ni = 1; ni < 4; ++ni)
      #pragma unroll
      for (int r = 0; r < 4; ++r) m4[r] = fmaxf(m4[r], sacc[ni][r]);
    float mloc = fmaxf(fmaxf(m4[0], m4[1]), fmaxf(m4[2], m4[3]));
    mloc = fmaxf(mloc, __shfl_xor(mloc, 16));
    mloc = fmaxf(mloc, __shfl_xor(mloc, 32));
    float mn = fmaxf(m_run, mloc);
    float scale = exp2f(m_run - mn);
    m_run = mn;
    #pragma unroll
    for (int ni = 0; ni < 4; ++ni)
      #pragma unroll
      for (int r = 0; r < 4; ++r) sacc[ni][r] = exp2f(sacc[ni][r] - mn);
    f32x4 s4 = sacc[0];
    #pragma unroll
    for (int ni = 1; ni < 4; ++ni)
      #pragma unroll
      for (int r = 0; r < 4; ++r) s4[r] += sacc[ni][r];
    float sloc = (s4[0] + s4[1]) + (s4[2] + s4[3]);
    sloc += __shfl_xor(sloc, 16);
    sloc += __shfl_xor(sloc, 32);
    l_run = l_run * scale + sloc;
    #pragma unroll
    for (int ni = 0; ni < 4; ++ni)
      #pragma unroll
      for (int r = 0; r < 4; ++r) o[ni][r] *= scale;

    // P^T -> LDS (wave-private; program-order lgkmcnt, no barrier)
    #pragma unroll
    for (int ni = 0; ni < 4; ++ni) {
      f16x4 pk;
      #pragma unroll
      for (int r = 0; r < 4; ++r) pk[r] = (f16)sacc[ni][r];
      *reinterpret_cast<f16x4*>(&Ps[w][lr * 72 + ni * 16 + orow]) = pk;
    }

    // O^T += V^T * P^T
    #pragma unroll
    for (int t = 0; t < 2; ++t) {
      f16x8 pf = *reinterpret_cast<const f16x8*>(&Ps[w][lr * 72 + t * 32 + lk]);
      #pragma unroll
      for (int ni = 0; ni < 4; ++ni) {
        f16x8 vf = *reinterpret_cast<const f16x8*>(Vs + (ni * 16 + lr) * 64 + ((t * 32 + lk) ^ swz));
        o[ni] = __builtin_amdgcn_mfma_f32_16x16x32_f16(vf, pf, o[ni], 0, 0, 0);
      }
    }
  }

  // epilogue: O^T = [col=q=lr][row=d=ni*16+orow+r] -> packed stores
  float rl = 1.0f / l_run;
  #pragma unroll
  for (int ni = 0; ni < 4; ++ni) {
    f16x4 ov;
    #pragma unroll
    for (int r = 0; r < 4; ++r) ov[r] = (f16)(o[ni][r] * rl);
    *reinterpret_cast<f16x4*>(
        &attn_out[(size_t)(b * S_ + qg) * D_ + h * HD_ + ni * 16 + orow]) = ov;
  }
}

// ---------------- launch --------------------------------------------
extern "C" void kernel_launch(void* const* d_in, const int* in_sizes, int n_in,
                              void* d_out, int out_size, void* d_ws, size_t ws_size,
                              hipStream_t stream) {
  const float* x    = (const float*)d_in[0];
  const int*   pos  = (const int*)d_in[1];
  const float* wqkv = (const float*)d_in[2];
  const float* wo   = (const float*)d_in[3];
  float* out = (float*)d_out;

  const size_t BHSD = (size_t)B_ * H_ * S_ * HD_;   // 8388608
  f16* xb    = (f16*)d_ws;                 // M_*D_
  f16* wqkvb = xb + (size_t)M_ * D_;       // NQKV_*D_
  f16* wob   = wqkvb + (size_t)NQKV_ * D_; // D_*D_
  f16* qb    = wob + (size_t)D_ * D_;      // BHSD
  f16* kb    = qb + BHSD;                  // BHSD
  f16* vtb   = kb + BHSD;                  // BHSD (B,H,hd,S)
  f16* attnb = vtb + BHSD;                 // BHSD
  float2* tab = (float2*)(attnb + BHSD);   // S_*32 float2 = 512 KB
  // total ~92 MB of d_ws

  cast_kernel<<<(M_ * D_) / 2048, 256, 0, stream>>>(x, xb);
  cast_kernel<<<(NQKV_ * D_) / 2048, 256, 0, stream>>>(wqkv, wqkvb);
  cast_kernel<<<(D_ * D_) / 2048, 256, 0, stream>>>(wo, wob);
  trig_kernel<<<(S_ * 32) / 256, 256, 0, stream>>>(pos, tab);

  gemm_bt<0><<<(M_ / 128) * (NQKV_ / 128), 256, 0, stream>>>(
      xb, wqkvb, (void*)qb, tab, kb, vtb, M_, NQKV_, D_);

  attn_kernel<<<64 * 32, 256, 0, stream>>>(qb, kb, vtb, attnb);

  gemm_bt<1><<<(M_ / 128) * (D_ / 128), 256, 0, stream>>>(
      attnb, wob, (void*)out, nullptr, nullptr, nullptr, M_, D_, D_);
}